// Round 3
// baseline (615.418 us; speedup 1.0000x reference)
//
#include <hip/hip_runtime.h>
#include <hip/hip_bf16.h>

#define H 512
#define B 64
#define S 2048

#define BM 128
#define BK 32

typedef __bf16 bf16x8 __attribute__((ext_vector_type(8)));
typedef float f32x4 __attribute__((ext_vector_type(4)));

__device__ __forceinline__ unsigned cvt2(float x, float y) {
    union { __hip_bfloat162 h; unsigned u; } cv;
    cv.h = __float22bfloat162_rn(make_float2(x, y));
    return cv.u;
}

__device__ __forceinline__ float fast_tanh(float x) {
    float e = __expf(2.0f * x);
    float r = __builtin_amdgcn_rcpf(e + 1.0f);
    return 1.0f - 2.0f * r;
}

// async global -> LDS, 16 bytes per lane (global_load_lds_dwordx4)
__device__ __forceinline__ void load_lds16(const void* g, void* l) {
    __builtin_amdgcn_global_load_lds(
        (const __attribute__((address_space(1))) unsigned int*)g,
        (__attribute__((address_space(3))) unsigned int*)l, 16, 0, 0);
}

// ---------------- prep: enc fp32 -> bf16 (streaming, BW-bound) ----------------
#define CVT_GRID 4096
__global__ __launch_bounds__(256) void cvt_kernel(const float* __restrict__ src,
                                                  __hip_bfloat16* __restrict__ dst) {
    size_t i = (size_t)blockIdx.x * 256 + threadIdx.x;
    const size_t stride = (size_t)CVT_GRID * 256;
    #pragma unroll
    for (int k = 0; k < 8; ++k, i += stride) {     // 8M float8-chunks total
        size_t e = i * 8;
        float4 a = *(const float4*)(src + e);
        float4 b = *(const float4*)(src + e + 4);
        uint4 p = make_uint4(cvt2(a.x, a.y), cvt2(a.z, a.w), cvt2(b.x, b.y), cvt2(b.z, b.w));
        *(uint4*)(dst + e) = p;
    }
}

// ---------------- u[b,k] = U_b[k]+W_b[k]+U_w[k,:]@hid[b,:]  (+ Ww->bf16 on b==0) ---
__global__ __launch_bounds__(256) void u_kernel(
        const float* __restrict__ hid, const float* __restrict__ Uw,
        const float* __restrict__ Ub, const float* __restrict__ Wb,
        float* __restrict__ u, const float* __restrict__ Ww,
        __hip_bfloat16* __restrict__ Wwb) {
    const int b = blockIdx.y;
    const int k = blockIdx.x * 4 + (threadIdx.x >> 6);
    const int lane = threadIdx.x & 63;
    if (Wwb != nullptr && b == 0) {               // 128 x-blocks * 2048 = 512*512 elems
        int base = (blockIdx.x * 256 + threadIdx.x) * 8;
        float4 a = *(const float4*)(Ww + base);
        float4 c = *(const float4*)(Ww + base + 4);
        uint4 p = make_uint4(cvt2(a.x, a.y), cvt2(a.z, a.w), cvt2(c.x, c.y), cvt2(c.z, c.w));
        *(uint4*)(Wwb + base) = p;
    }
    const float4* wrow = (const float4*)(Uw + (size_t)k * H);
    const float4* hrow = (const float4*)(hid + (size_t)b * H);
    float4 w0 = wrow[lane * 2], w1 = wrow[lane * 2 + 1];
    float4 h0 = hrow[lane * 2], h1 = hrow[lane * 2 + 1];
    float acc = w0.x * h0.x + w0.y * h0.y + w0.z * h0.z + w0.w * h0.w
              + w1.x * h1.x + w1.y * h1.y + w1.z * h1.z + w1.w * h1.w;
    #pragma unroll
    for (int off = 1; off < 64; off <<= 1) acc += __shfl_xor(acc, off, 64);
    if (lane == 0) u[b * H + k] = acc + Ub[k] + Wb[k];
}

// ---------------- energy: bf16 MFMA GEMM + tanh epilogue (m97 staging) ----------
__global__ __launch_bounds__(256, 4) void energy_kernel(
        const __hip_bfloat16* __restrict__ encb, const __hip_bfloat16* __restrict__ Wwb,
        const float* __restrict__ Vw, const float* __restrict__ u,
        float* __restrict__ energy) {
    const int st = blockIdx.x;        // 0..15
    const int b  = blockIdx.y;        // 0..63
    const int s0 = st * BM;
    const int tid  = threadIdx.x;
    const int wave = tid >> 6;
    const int lane = tid & 63;
    const int wr = wave >> 1, wc = wave & 1;
    const int quad = lane >> 4, c = lane & 15;

    __shared__ __hip_bfloat16 As[BM * BK];   // 8KB, row-major [row][32]
    __shared__ __hip_bfloat16 Bs[BM * BK];   // 8KB
    __shared__ float uS[H], vS[H];           // 4KB
    __shared__ float red[BM];

    #pragma unroll
    for (int i = tid; i < H; i += 256) { uS[i] = u[b * H + i]; vS[i] = Vw[i]; }

    // staging geometry: wave w fills chunks q=2w,2w+1 (16 rows x 64B each)
    const int arow  = lane >> 2;             // 0..15 row within chunk
    const int acol  = (lane & 3) * 8;        // bf16 col offset (16B granules)
    const int lds0  = wave * 1024 + lane * 8;     // elements; = chunk q0 base + lane*16B
    const int lds1  = lds0 + 512;                  // chunk q0+1
    const size_t ga0 = ((size_t)(b * S + s0) + wave * 32 + arow) * H + acol;
    const size_t ga1 = ga0 + (size_t)16 * H;

    float esum[4][4] = {};

    for (int kt = 0; kt < 4; ++kt) {
        const size_t gb0 = ((size_t)(kt * BM) + wave * 32 + arow) * H + acol;
        const size_t gb1 = gb0 + (size_t)16 * H;
        f32x4 acc[4][4] = {};

        for (int kk = 0; kk < H / BK; ++kk) {
            const int h0 = kk * BK;
            __syncthreads();                       // prev readers done (also covers uS init)
            load_lds16(encb + ga0 + h0, &As[lds0]);
            load_lds16(encb + ga1 + h0, &As[lds1]);
            load_lds16(Wwb + gb0 + h0, &Bs[lds0]);
            load_lds16(Wwb + gb1 + h0, &Bs[lds1]);
            __syncthreads();                       // vmcnt(0) drain -> LDS visible
            bf16x8 af[4], bfr[4];
            #pragma unroll
            for (int i = 0; i < 4; ++i)
                af[i] = *(const bf16x8*)&As[(wr * 64 + i * 16 + c) * BK + quad * 8];
            #pragma unroll
            for (int j = 0; j < 4; ++j)
                bfr[j] = *(const bf16x8*)&Bs[(wc * 64 + j * 16 + c) * BK + quad * 8];
            #pragma unroll
            for (int i = 0; i < 4; ++i)
                #pragma unroll
                for (int j = 0; j < 4; ++j)
                    acc[i][j] = __builtin_amdgcn_mfma_f32_16x16x32_bf16(af[i], bfr[j], acc[i][j], 0, 0, 0);
        }

        #pragma unroll
        for (int i = 0; i < 4; ++i)
            #pragma unroll
            for (int j = 0; j < 4; ++j) {
                const int col = kt * BM + wc * 64 + j * 16 + c;
                const float v = vS[col], uu = uS[col];
                #pragma unroll
                for (int r = 0; r < 4; ++r)
                    esum[i][r] += v * fast_tanh(uu + acc[i][j][r]);
            }
    }

    #pragma unroll
    for (int i = 0; i < 4; ++i)
        #pragma unroll
        for (int r = 0; r < 4; ++r) {
            float e = esum[i][r];
            e += __shfl_xor(e, 1, 64);
            e += __shfl_xor(e, 2, 64);
            e += __shfl_xor(e, 4, 64);
            e += __shfl_xor(e, 8, 64);
            esum[i][r] = e;
        }
    __syncthreads();
    if (wc == 0 && c == 0) {
        #pragma unroll
        for (int i = 0; i < 4; ++i)
            #pragma unroll
            for (int r = 0; r < 4; ++r)
                red[wr * 64 + i * 16 + quad * 4 + r] = esum[i][r];
    }
    __syncthreads();
    if (wc == 1 && c == 0) {
        #pragma unroll
        for (int i = 0; i < 4; ++i)
            #pragma unroll
            for (int r = 0; r < 4; ++r) {
                const int row = wr * 64 + i * 16 + quad * 4 + r;
                energy[b * S + s0 + row] = red[row] + esum[i][r];
            }
    }
}

// ---------------- fallback energy (round-2, fp32 staging) -----------------------
__global__ __launch_bounds__(256) void energy_f32_kernel(
        const float* __restrict__ enc, const float* __restrict__ Ww,
        const float* __restrict__ Vw, const float* __restrict__ u,
        float* __restrict__ energy) {
    const int st = blockIdx.x, b = blockIdx.y;
    const int s0 = st * BM;
    const int tid = threadIdx.x, wave = tid >> 6, lane = tid & 63;
    const int wr = wave >> 1, wc = wave & 1, quad = lane >> 4, c = lane & 15;
    __shared__ unsigned short As[BM][BK];
    __shared__ unsigned short Bs[BM][BK];
    __shared__ float uS[H], vS[H], red[BM];
    for (int i = tid; i < H; i += 256) { uS[i] = u[b * H + i]; vS[i] = Vw[i]; }
    const int srow = tid >> 3, sc4 = (tid & 7) * 4;
    const float* pA = enc + ((size_t)(b * S + s0) + srow) * H + sc4;
    float esum[4][4] = {};
    for (int kt = 0; kt < 4; ++kt) {
        const float* pB = Ww + ((size_t)(kt * BM) + srow) * H + sc4;
        f32x4 acc[4][4] = {};
        for (int kk = 0; kk < H / BK; ++kk) {
            const int h0 = kk * BK;
            uint2 ap[4], bp[4];
            #pragma unroll
            for (int i = 0; i < 4; ++i) {
                float4 a4 = *(const float4*)(pA + (size_t)i * 32 * H + h0);
                float4 b4 = *(const float4*)(pB + (size_t)i * 32 * H + h0);
                ap[i].x = cvt2(a4.x, a4.y); ap[i].y = cvt2(a4.z, a4.w);
                bp[i].x = cvt2(b4.x, b4.y); bp[i].y = cvt2(b4.z, b4.w);
            }
            __syncthreads();
            #pragma unroll
            for (int i = 0; i < 4; ++i) {
                *(uint2*)&As[srow + i * 32][sc4] = ap[i];
                *(uint2*)&Bs[srow + i * 32][sc4] = bp[i];
            }
            __syncthreads();
            bf16x8 af[4], bfr[4];
            #pragma unroll
            for (int i = 0; i < 4; ++i) af[i]  = *(const bf16x8*)&As[wr * 64 + i * 16 + c][quad * 8];
            #pragma unroll
            for (int j = 0; j < 4; ++j) bfr[j] = *(const bf16x8*)&Bs[wc * 64 + j * 16 + c][quad * 8];
            #pragma unroll
            for (int i = 0; i < 4; ++i)
                #pragma unroll
                for (int j = 0; j < 4; ++j)
                    acc[i][j] = __builtin_amdgcn_mfma_f32_16x16x32_bf16(af[i], bfr[j], acc[i][j], 0, 0, 0);
        }
        #pragma unroll
        for (int i = 0; i < 4; ++i)
            #pragma unroll
            for (int j = 0; j < 4; ++j) {
                const int col = kt * BM + wc * 64 + j * 16 + c;
                const float v = vS[col], uu = uS[col];
                #pragma unroll
                for (int r = 0; r < 4; ++r) esum[i][r] += v * fast_tanh(uu + acc[i][j][r]);
            }
    }
    #pragma unroll
    for (int i = 0; i < 4; ++i)
        #pragma unroll
        for (int r = 0; r < 4; ++r) {
            float e = esum[i][r];
            e += __shfl_xor(e, 1, 64); e += __shfl_xor(e, 2, 64);
            e += __shfl_xor(e, 4, 64); e += __shfl_xor(e, 8, 64);
            esum[i][r] = e;
        }
    __syncthreads();
    if (wc == 0 && c == 0)
        for (int i = 0; i < 4; ++i)
            for (int r = 0; r < 4; ++r)
                red[wr * 64 + i * 16 + quad * 4 + r] = esum[i][r];
    __syncthreads();
    if (wc == 1 && c == 0)
        for (int i = 0; i < 4; ++i)
            for (int r = 0; r < 4; ++r) {
                const int row = wr * 64 + i * 16 + quad * 4 + r;
                energy[b * S + s0 + row] = red[row] + esum[i][r];
            }
}

// ---------------- softmax over S per batch --------------------------------------
__global__ void softmax_kernel(const float* __restrict__ energy, float* __restrict__ attn) {
    int b = blockIdx.x, t = threadIdx.x;
    const float* e = energy + b * S;
    float v[8]; float m = -1e30f;
    #pragma unroll
    for (int i = 0; i < 8; ++i) { v[i] = e[t + i * 256]; m = fmaxf(m, v[i]); }
    #pragma unroll
    for (int off = 1; off < 64; off <<= 1) m = fmaxf(m, __shfl_xor(m, off, 64));
    __shared__ float redm[4], reds[4];
    if ((t & 63) == 0) redm[t >> 6] = m;
    __syncthreads();
    m = fmaxf(fmaxf(redm[0], redm[1]), fmaxf(redm[2], redm[3]));
    float s = 0.f;
    #pragma unroll
    for (int i = 0; i < 8; ++i) { v[i] = __expf(v[i] - m); s += v[i]; }
    #pragma unroll
    for (int off = 1; off < 64; off <<= 1) s += __shfl_xor(s, off, 64);
    if ((t & 63) == 0) reds[t >> 6] = s;
    __syncthreads();
    float inv = 1.0f / (reds[0] + reds[1] + reds[2] + reds[3]);
    #pragma unroll
    for (int i = 0; i < 8; ++i) attn[b * S + t + i * 256] = v[i] * inv;
}

// ---------------- context from bf16 enc copy ------------------------------------
__global__ __launch_bounds__(256) void context_bf16_kernel(
        const __hip_bfloat16* __restrict__ encb, const float* __restrict__ attn,
        float* __restrict__ ctx) {
    const int b = blockIdx.x >> 4, ch = blockIdx.x & 15;   // 128 rows/chunk
    const int t = threadIdx.x;
    const int col8 = (t & 63) * 8, rg = t >> 6;            // 4 row-groups
    __shared__ float aS[128];
    __shared__ float part[4][H];
    if (t < 128) aS[t] = attn[b * S + ch * 128 + t];
    __syncthreads();
    const size_t rbase = (size_t)(b * S + ch * 128) * H;
    float c0[8] = {};
    #pragma unroll 4
    for (int i = 0; i < 32; ++i) {
        int s = rg * 32 + i;
        bf16x8 ev = *(const bf16x8*)(encb + rbase + (size_t)s * H + col8);
        float a = aS[s];
        #pragma unroll
        for (int j = 0; j < 8; ++j) c0[j] += a * (float)ev[j];
    }
    #pragma unroll
    for (int j = 0; j < 8; ++j) part[rg][col8 + j] = c0[j];
    __syncthreads();
    // 256 threads reduce 512 cols (2 each) over 4 row-groups
    #pragma unroll
    for (int j = 0; j < 2; ++j) {
        int col = t * 2 + j;
        atomicAdd(&ctx[b * H + col], part[0][col] + part[1][col] + part[2][col] + part[3][col]);
    }
}

__global__ __launch_bounds__(256) void context_f32_kernel(
        const float* __restrict__ enc, const float* __restrict__ attn,
        float* __restrict__ ctx) {
    int b = blockIdx.x >> 4, ch = blockIdx.x & 15, t = threadIdx.x;
    __shared__ float aS[128];
    if (t < 128) aS[t] = attn[b * S + ch * 128 + t];
    __syncthreads();
    const float* ebase = enc + ((size_t)(b * S + ch * 128)) * H + t;
    float c0 = 0.f, c1 = 0.f;
    #pragma unroll 8
    for (int s = 0; s < 128; ++s) {
        float a = aS[s];
        c0 += a * ebase[(size_t)s * H];
        c1 += a * ebase[(size_t)s * H + 256];
    }
    atomicAdd(&ctx[b * H + t], c0);
    atomicAdd(&ctx[b * H + t + 256], c1);
}

extern "C" void kernel_launch(void* const* d_in, const int* in_sizes, int n_in,
                              void* d_out, int out_size, void* d_ws, size_t ws_size,
                              hipStream_t stream) {
    (void)in_sizes; (void)n_in; (void)out_size;
    const float* hid = (const float*)d_in[0];
    const float* enc = (const float*)d_in[1];
    const float* Uw  = (const float*)d_in[2];
    const float* Ub  = (const float*)d_in[3];
    const float* Ww  = (const float*)d_in[4];
    const float* Wb  = (const float*)d_in[5];
    const float* Vw  = (const float*)d_in[6];
    // V_b unused: softmax shift-invariant, energy not an output.

    float* out_ctx  = (float*)d_out;                   // 64*512
    float* out_attn = out_ctx + B * H;                 // 64*2048
    char*  ws       = (char*)d_ws;
    float* energy   = (float*)ws;                      // 512 KB
    float* u        = (float*)(ws + 524288);           // 128 KB
    __hip_bfloat16* encb = (__hip_bfloat16*)(ws + 655360);            // 128 MB
    __hip_bfloat16* Wwb  = (__hip_bfloat16*)(ws + 655360 + 134217728); // 512 KB
    const size_t need = 655360 + 134217728 + 524288;
    const bool fast = ws_size >= need;

    hipMemsetAsync(d_out, 0, (size_t)B * H * sizeof(float), stream);   // ctx accum target

    if (fast) {
        cvt_kernel<<<CVT_GRID, 256, 0, stream>>>(enc, encb);
        u_kernel<<<dim3(H / 4, B), 256, 0, stream>>>(hid, Uw, Ub, Wb, u, Ww, Wwb);
        energy_kernel<<<dim3(S / BM, B), 256, 0, stream>>>(encb, Wwb, Vw, u, energy);
        softmax_kernel<<<B, 256, 0, stream>>>(energy, out_attn);
        context_bf16_kernel<<<B * 16, 256, 0, stream>>>(encb, out_attn, out_ctx);
    } else {
        u_kernel<<<dim3(H / 4, B), 256, 0, stream>>>(hid, Uw, Ub, Wb, u, Ww, nullptr);
        energy_f32_kernel<<<dim3(S / BM, B), 256, 0, stream>>>(enc, Ww, Vw, u, energy);
        softmax_kernel<<<B, 256, 0, stream>>>(energy, out_attn);
        context_f32_kernel<<<B * 16, 256, 0, stream>>>(enc, out_attn, out_ctx);
    }
}

// Round 4
// 572.230 us; speedup vs baseline: 1.0755x; 1.0755x over previous
//
#include <hip/hip_runtime.h>
#include <hip/hip_bf16.h>

#define H 512
#define B 64
#define S 2048

#define BM 128

typedef __bf16 bf16x8 __attribute__((ext_vector_type(8)));
typedef float f32x4 __attribute__((ext_vector_type(4)));
typedef float fv4 __attribute__((ext_vector_type(4)));

__device__ __forceinline__ unsigned cvt2(float x, float y) {
    union { __hip_bfloat162 h; unsigned u; } cv;
    cv.h = __float22bfloat162_rn(make_float2(x, y));
    return cv.u;
}

__device__ __forceinline__ float fast_tanh(float x) {
    float e = __expf(2.0f * x);
    float r = __builtin_amdgcn_rcpf(e + 1.0f);
    return 1.0f - 2.0f * r;
}

// async global -> LDS, 16 B/lane. aux: 0 = default, 2 = NT (non-temporal, CPol bit1)
__device__ __forceinline__ void load_lds16(const void* g, void* l, int aux) {
    if (aux == 2)
        __builtin_amdgcn_global_load_lds(
            (const __attribute__((address_space(1))) unsigned int*)g,
            (__attribute__((address_space(3))) unsigned int*)l, 16, 0, 2);
    else
        __builtin_amdgcn_global_load_lds(
            (const __attribute__((address_space(1))) unsigned int*)g,
            (__attribute__((address_space(3))) unsigned int*)l, 16, 0, 0);
}

// ---------------- prep: enc fp32 -> bf16 (streaming; NT reads, cacheable writes) ----
#define CVT_GRID 4096
__global__ __launch_bounds__(256) void cvt_kernel(const float* __restrict__ src,
                                                  __hip_bfloat16* __restrict__ dst) {
    size_t i = (size_t)blockIdx.x * 256 + threadIdx.x;
    const size_t stride = (size_t)CVT_GRID * 256;
    #pragma unroll
    for (int k = 0; k < 8; ++k, i += stride) {
        size_t e = i * 8;
        fv4 a = __builtin_nontemporal_load((const fv4*)(src + e));
        fv4 b = __builtin_nontemporal_load((const fv4*)(src + e + 4));
        uint4 p = make_uint4(cvt2(a.x, a.y), cvt2(a.z, a.w), cvt2(b.x, b.y), cvt2(b.z, b.w));
        *(uint4*)(dst + e) = p;
    }
}

// ---------------- u[b,k] = U_b[k]+W_b[k]+U_w[k,:]@hid[b,:]  (+ Ww->bf16 on b==0) ---
__global__ __launch_bounds__(256) void u_kernel(
        const float* __restrict__ hid, const float* __restrict__ Uw,
        const float* __restrict__ Ub, const float* __restrict__ Wb,
        float* __restrict__ u, const float* __restrict__ Ww,
        __hip_bfloat16* __restrict__ Wwb) {
    const int b = blockIdx.y;
    const int k = blockIdx.x * 4 + (threadIdx.x >> 6);
    const int lane = threadIdx.x & 63;
    if (Wwb != nullptr && b == 0) {
        int base = (blockIdx.x * 256 + threadIdx.x) * 8;
        float4 a = *(const float4*)(Ww + base);
        float4 c = *(const float4*)(Ww + base + 4);
        uint4 p = make_uint4(cvt2(a.x, a.y), cvt2(a.z, a.w), cvt2(c.x, c.y), cvt2(c.z, c.w));
        *(uint4*)(Wwb + base) = p;
    }
    const float4* wrow = (const float4*)(Uw + (size_t)k * H);
    const float4* hrow = (const float4*)(hid + (size_t)b * H);
    float4 w0 = wrow[lane * 2], w1 = wrow[lane * 2 + 1];
    float4 h0 = hrow[lane * 2], h1 = hrow[lane * 2 + 1];
    float acc = w0.x * h0.x + w0.y * h0.y + w0.z * h0.z + w0.w * h0.w
              + w1.x * h1.x + w1.y * h1.y + w1.z * h1.z + w1.w * h1.w;
    #pragma unroll
    for (int off = 1; off < 64; off <<= 1) acc += __shfl_xor(acc, off, 64);
    if (lane == 0) u[b * H + k] = acc + Ub[k] + Wb[k];
}

// ---------------- energy: bf16 MFMA GEMM + tanh epilogue ------------------------
// BK=64, XOR-swizzled 16B granules (conflict-free ds_read_b128),
// NT on A staging (protects Wwb in L2).
__global__ __launch_bounds__(256, 4) void energy_kernel(
        const __hip_bfloat16* __restrict__ encb, const __hip_bfloat16* __restrict__ Wwb,
        const float* __restrict__ Vw, const float* __restrict__ u,
        float* __restrict__ energy) {
    const int st = blockIdx.x;        // 0..15
    const int b  = blockIdx.y;        // 0..63
    const int s0 = st * BM;
    const int tid  = threadIdx.x;
    const int wave = tid >> 6;
    const int lane = tid & 63;
    const int wr = wave >> 1, wc = wave & 1;
    const int quad = lane >> 4, c = lane & 15;

    __shared__ __hip_bfloat16 As[BM * 64];   // 16KB, row-major [row][64], granule-swizzled
    __shared__ __hip_bfloat16 Bs[BM * 64];   // 16KB
    __shared__ float uS[H], vS[H];           // 4KB
    __shared__ float red[BM];

    #pragma unroll
    for (int i = tid; i < H; i += 256) { uS[i] = u[b * H + i]; vS[i] = Vw[i]; }

    // staging: chunk = 8 rows x 128B = 1024B = one load_lds16 per wave.
    // lane l -> row (chunk*8 + (l>>3)), physical granule (l&7); fetches LOGICAL
    // granule (l&7)^(l>>3 &7) so phys = log ^ (row&7)  (XOR bank swizzle).
    const int rl = lane >> 3;                    // row within chunk = row&7
    const int gl = (lane & 7) ^ rl;              // logical granule to fetch
    const int colb = gl * 8;                     // bf16 col offset within 64-col K-block
    const int q0 = wave * 4;                     // this wave's first chunk
    const size_t gArow = ((size_t)(b * S + s0) + q0 * 8 + rl) * H + colb;

    // fragment un-swizzle: phys granule for (quad, k-half s) at row r: (quad+4s)^(r&7)
    const int cb = c & 7;
    const int pa0 = ((quad) ^ cb) * 8;           // element offset, s=0
    const int pa1 = ((quad + 4) ^ cb) * 8;       // s=1

    float esum[4][4] = {};

    for (int kt = 0; kt < 4; ++kt) {
        const size_t gBrow = ((size_t)(kt * BM) + q0 * 8 + rl) * H + colb;
        f32x4 acc[4][4] = {};

        for (int kk = 0; kk < 8; ++kk) {         // K = 512 / 64
            const int h0 = kk * 64;
            __syncthreads();                     // prev readers done (covers uS init on kk==0)
            #pragma unroll
            for (int i = 0; i < 4; ++i) {
                load_lds16(encb + gArow + (size_t)i * 8 * H + h0, &As[(q0 + i) * 512 + lane * 8], 2); // NT
                load_lds16(Wwb  + gBrow + (size_t)i * 8 * H + h0, &Bs[(q0 + i) * 512 + lane * 8], 0);
            }
            __syncthreads();                     // vmcnt(0) drain
            #pragma unroll
            for (int s = 0; s < 2; ++s) {
                const int po = s ? pa1 : pa0;
                bf16x8 af[4], bfr[4];
                #pragma unroll
                for (int i = 0; i < 4; ++i)
                    af[i] = *(const bf16x8*)&As[(wr * 64 + i * 16 + c) * 64 + po];
                #pragma unroll
                for (int j = 0; j < 4; ++j)
                    bfr[j] = *(const bf16x8*)&Bs[(wc * 64 + j * 16 + c) * 64 + po];
                #pragma unroll
                for (int i = 0; i < 4; ++i)
                    #pragma unroll
                    for (int j = 0; j < 4; ++j)
                        acc[i][j] = __builtin_amdgcn_mfma_f32_16x16x32_bf16(af[i], bfr[j], acc[i][j], 0, 0, 0);
            }
        }

        #pragma unroll
        for (int i = 0; i < 4; ++i)
            #pragma unroll
            for (int j = 0; j < 4; ++j) {
                const int col = kt * BM + wc * 64 + j * 16 + c;
                const float v = vS[col], uu = uS[col];
                #pragma unroll
                for (int r = 0; r < 4; ++r)
                    esum[i][r] += v * fast_tanh(uu + acc[i][j][r]);
            }
    }

    #pragma unroll
    for (int i = 0; i < 4; ++i)
        #pragma unroll
        for (int r = 0; r < 4; ++r) {
            float e = esum[i][r];
            e += __shfl_xor(e, 1, 64);
            e += __shfl_xor(e, 2, 64);
            e += __shfl_xor(e, 4, 64);
            e += __shfl_xor(e, 8, 64);
            esum[i][r] = e;
        }
    __syncthreads();
    if (wc == 0 && c == 0) {
        #pragma unroll
        for (int i = 0; i < 4; ++i)
            #pragma unroll
            for (int r = 0; r < 4; ++r)
                red[wr * 64 + i * 16 + quad * 4 + r] = esum[i][r];
    }
    __syncthreads();
    if (wc == 1 && c == 0) {
        #pragma unroll
        for (int i = 0; i < 4; ++i)
            #pragma unroll
            for (int r = 0; r < 4; ++r) {
                const int row = wr * 64 + i * 16 + quad * 4 + r;
                energy[b * S + s0 + row] = red[row] + esum[i][r];
            }
    }
}

// ---------------- fallback energy (fp32 inline-cvt staging, BK=32) --------------
#define BK32 32
__global__ __launch_bounds__(256) void energy_f32_kernel(
        const float* __restrict__ enc, const float* __restrict__ Ww,
        const float* __restrict__ Vw, const float* __restrict__ u,
        float* __restrict__ energy) {
    const int st = blockIdx.x, b = blockIdx.y;
    const int s0 = st * BM;
    const int tid = threadIdx.x, wave = tid >> 6, lane = tid & 63;
    const int wr = wave >> 1, wc = wave & 1, quad = lane >> 4, c = lane & 15;
    __shared__ unsigned short As[BM][BK32];
    __shared__ unsigned short Bs[BM][BK32];
    __shared__ float uS[H], vS[H], red[BM];
    for (int i = tid; i < H; i += 256) { uS[i] = u[b * H + i]; vS[i] = Vw[i]; }
    const int srow = tid >> 3, sc4 = (tid & 7) * 4;
    const float* pA = enc + ((size_t)(b * S + s0) + srow) * H + sc4;
    float esum[4][4] = {};
    for (int kt = 0; kt < 4; ++kt) {
        const float* pB = Ww + ((size_t)(kt * BM) + srow) * H + sc4;
        f32x4 acc[4][4] = {};
        for (int kk = 0; kk < H / BK32; ++kk) {
            const int h0 = kk * BK32;
            uint2 ap[4], bp[4];
            #pragma unroll
            for (int i = 0; i < 4; ++i) {
                float4 a4 = *(const float4*)(pA + (size_t)i * 32 * H + h0);
                float4 b4 = *(const float4*)(pB + (size_t)i * 32 * H + h0);
                ap[i].x = cvt2(a4.x, a4.y); ap[i].y = cvt2(a4.z, a4.w);
                bp[i].x = cvt2(b4.x, b4.y); bp[i].y = cvt2(b4.z, b4.w);
            }
            __syncthreads();
            #pragma unroll
            for (int i = 0; i < 4; ++i) {
                *(uint2*)&As[srow + i * 32][sc4] = ap[i];
                *(uint2*)&Bs[srow + i * 32][sc4] = bp[i];
            }
            __syncthreads();
            bf16x8 af[4], bfr[4];
            #pragma unroll
            for (int i = 0; i < 4; ++i) af[i]  = *(const bf16x8*)&As[wr * 64 + i * 16 + c][quad * 8];
            #pragma unroll
            for (int j = 0; j < 4; ++j) bfr[j] = *(const bf16x8*)&Bs[wc * 64 + j * 16 + c][quad * 8];
            #pragma unroll
            for (int i = 0; i < 4; ++i)
                #pragma unroll
                for (int j = 0; j < 4; ++j)
                    acc[i][j] = __builtin_amdgcn_mfma_f32_16x16x32_bf16(af[i], bfr[j], acc[i][j], 0, 0, 0);
        }
        #pragma unroll
        for (int i = 0; i < 4; ++i)
            #pragma unroll
            for (int j = 0; j < 4; ++j) {
                const int col = kt * BM + wc * 64 + j * 16 + c;
                const float v = vS[col], uu = uS[col];
                #pragma unroll
                for (int r = 0; r < 4; ++r) esum[i][r] += v * fast_tanh(uu + acc[i][j][r]);
            }
    }
    #pragma unroll
    for (int i = 0; i < 4; ++i)
        #pragma unroll
        for (int r = 0; r < 4; ++r) {
            float e = esum[i][r];
            e += __shfl_xor(e, 1, 64); e += __shfl_xor(e, 2, 64);
            e += __shfl_xor(e, 4, 64); e += __shfl_xor(e, 8, 64);
            esum[i][r] = e;
        }
    __syncthreads();
    if (wc == 0 && c == 0)
        for (int i = 0; i < 4; ++i)
            for (int r = 0; r < 4; ++r)
                red[wr * 64 + i * 16 + quad * 4 + r] = esum[i][r];
    __syncthreads();
    if (wc == 1 && c == 0)
        for (int i = 0; i < 4; ++i)
            for (int r = 0; r < 4; ++r) {
                const int row = wr * 64 + i * 16 + quad * 4 + r;
                energy[b * S + s0 + row] = red[row] + esum[i][r];
            }
}

// ---------------- softmax over S per batch --------------------------------------
__global__ void softmax_kernel(const float* __restrict__ energy, float* __restrict__ attn) {
    int b = blockIdx.x, t = threadIdx.x;
    const float* e = energy + b * S;
    float v[8]; float m = -1e30f;
    #pragma unroll
    for (int i = 0; i < 8; ++i) { v[i] = e[t + i * 256]; m = fmaxf(m, v[i]); }
    #pragma unroll
    for (int off = 1; off < 64; off <<= 1) m = fmaxf(m, __shfl_xor(m, off, 64));
    __shared__ float redm[4], reds[4];
    if ((t & 63) == 0) redm[t >> 6] = m;
    __syncthreads();
    m = fmaxf(fmaxf(redm[0], redm[1]), fmaxf(redm[2], redm[3]));
    float s = 0.f;
    #pragma unroll
    for (int i = 0; i < 8; ++i) { v[i] = __expf(v[i] - m); s += v[i]; }
    #pragma unroll
    for (int off = 1; off < 64; off <<= 1) s += __shfl_xor(s, off, 64);
    if ((t & 63) == 0) reds[t >> 6] = s;
    __syncthreads();
    float inv = 1.0f / (reds[0] + reds[1] + reds[2] + reds[3]);
    #pragma unroll
    for (int i = 0; i < 8; ++i) attn[b * S + t + i * 256] = v[i] * inv;
}

// ---------------- context from bf16 enc copy ------------------------------------
__global__ __launch_bounds__(256) void context_bf16_kernel(
        const __hip_bfloat16* __restrict__ encb, const float* __restrict__ attn,
        float* __restrict__ ctx) {
    const int b = blockIdx.x >> 4, ch = blockIdx.x & 15;   // 128 rows/chunk
    const int t = threadIdx.x;
    const int col8 = (t & 63) * 8, rg = t >> 6;            // 4 row-groups
    __shared__ float aS[128];
    __shared__ float part[4][H];
    if (t < 128) aS[t] = attn[b * S + ch * 128 + t];
    __syncthreads();
    const size_t rbase = (size_t)(b * S + ch * 128) * H;
    float c0[8] = {};
    #pragma unroll 4
    for (int i = 0; i < 32; ++i) {
        int s = rg * 32 + i;
        bf16x8 ev = *(const bf16x8*)(encb + rbase + (size_t)s * H + col8);
        float a = aS[s];
        #pragma unroll
        for (int j = 0; j < 8; ++j) c0[j] += a * (float)ev[j];
    }
    #pragma unroll
    for (int j = 0; j < 8; ++j) part[rg][col8 + j] = c0[j];
    __syncthreads();
    #pragma unroll
    for (int j = 0; j < 2; ++j) {
        int col = t * 2 + j;
        atomicAdd(&ctx[b * H + col], part[0][col] + part[1][col] + part[2][col] + part[3][col]);
    }
}

__global__ __launch_bounds__(256) void context_f32_kernel(
        const float* __restrict__ enc, const float* __restrict__ attn,
        float* __restrict__ ctx) {
    int b = blockIdx.x >> 4, ch = blockIdx.x & 15, t = threadIdx.x;
    __shared__ float aS[128];
    if (t < 128) aS[t] = attn[b * S + ch * 128 + t];
    __syncthreads();
    const float* ebase = enc + ((size_t)(b * S + ch * 128)) * H + t;
    float c0 = 0.f, c1 = 0.f;
    #pragma unroll 8
    for (int s = 0; s < 128; ++s) {
        float a = aS[s];
        c0 += a * ebase[(size_t)s * H];
        c1 += a * ebase[(size_t)s * H + 256];
    }
    atomicAdd(&ctx[b * H + t], c0);
    atomicAdd(&ctx[b * H + t + 256], c1);
}

extern "C" void kernel_launch(void* const* d_in, const int* in_sizes, int n_in,
                              void* d_out, int out_size, void* d_ws, size_t ws_size,
                              hipStream_t stream) {
    (void)in_sizes; (void)n_in; (void)out_size;
    const float* hid = (const float*)d_in[0];
    const float* enc = (const float*)d_in[1];
    const float* Uw  = (const float*)d_in[2];
    const float* Ub  = (const float*)d_in[3];
    const float* Ww  = (const float*)d_in[4];
    const float* Wb  = (const float*)d_in[5];
    const float* Vw  = (const float*)d_in[6];
    // V_b unused: softmax shift-invariant, energy not an output.

    float* out_ctx  = (float*)d_out;                   // 64*512
    float* out_attn = out_ctx + B * H;                 // 64*2048
    char*  ws       = (char*)d_ws;
    float* energy   = (float*)ws;                      // 512 KB
    float* u        = (float*)(ws + 524288);           // 128 KB
    __hip_bfloat16* encb = (__hip_bfloat16*)(ws + 655360);             // 128 MB
    __hip_bfloat16* Wwb  = (__hip_bfloat16*)(ws + 655360 + 134217728); // 512 KB
    const size_t need = 655360 + 134217728 + 524288;
    const bool fast = ws_size >= need;

    hipMemsetAsync(d_out, 0, (size_t)B * H * sizeof(float), stream);   // ctx accum target

    if (fast) {
        cvt_kernel<<<CVT_GRID, 256, 0, stream>>>(enc, encb);
        u_kernel<<<dim3(H / 4, B), 256, 0, stream>>>(hid, Uw, Ub, Wb, u, Ww, Wwb);
        energy_kernel<<<dim3(S / BM, B), 256, 0, stream>>>(encb, Wwb, Vw, u, energy);
        softmax_kernel<<<B, 256, 0, stream>>>(energy, out_attn);
        context_bf16_kernel<<<B * 16, 256, 0, stream>>>(encb, out_attn, out_ctx);
    } else {
        u_kernel<<<dim3(H / 4, B), 256, 0, stream>>>(hid, Uw, Ub, Wb, u, Ww, nullptr);
        energy_f32_kernel<<<dim3(S / BM, B), 256, 0, stream>>>(enc, Ww, Vw, u, energy);
        softmax_kernel<<<B, 256, 0, stream>>>(energy, out_attn);
        context_f32_kernel<<<B * 16, 256, 0, stream>>>(enc, out_attn, out_ctx);
    }
}